// Round 5
// baseline (441.978 us; speedup 1.0000x reference)
//
#include <hip/hip_runtime.h>
#include <math.h>

#ifndef M_PI
#define M_PI 3.14159265358979323846
#endif

// Geometry fixed by the reference
#define NSLICE 16
#define WW     128
#define NANG   128
#define GP     130    // s_g row pitch (floats)
#define AB     16     // angles per chunk
#define PAD    27     // biased u in [0.7, 180.3] -> ii in [0,180]
#define SLOTS  183    // 8B slots per row: logical slots -1..181
#define SLOTF  (SLOTS*2) // dwords per row = 366 (row stride 1464 B, 8B aligned)

// One block per (c, h, half-image). 256 thr, 32 consecutive-X px/thread.
// Rows: fp16 (p0,d) entries duplicated into 8B slots; slot i = (e_i, e_{i+1}).
// One aligned ds_read_b64 serves TWO samples (|du|=|cs|<=1 -> index step in {0,1}).
__global__ __launch_bounds__(256, 4)
void fbp_fused(const float* __restrict__ F, float* __restrict__ out) {
    __shared__ __align__(16) unsigned s_rows[AB * SLOTF]; // 23424 B
    __shared__ float s_g[NSLICE][GP];
    __shared__ float s_h[WW];
    __shared__ float s_cs[NANG];
    __shared__ float s_sn[NANG];

    float* s_cos = (float*)s_rows;          // [128]    (phase 0 overlay)
    float* s_raw = (float*)s_rows + 128;    // [16*129] (phase 0 overlay)

    const int t   = threadIdx.x;
    const int blk = blockIdx.x;       // 0..2047
    const int q   = blk & 1;          // image half in X
    const int hh  = (blk >> 1) & 127;
    const int c   = blk >> 8;

    // ---- phase 0a: stage 16 feature rows F[s,0,c,hh,:] + tables ----
    const float* Fb = F + (((size_t)c * 128 + hh) * 128);
    #pragma unroll
    for (int e = 0; e < 8; ++e) {
        int idx = t + 256 * e;
        int s = idx >> 7, m = idx & 127;
        s_raw[s * 129 + m] = Fb[(size_t)s * 131072 + m];
    }
    if (t < 128) {
        s_cos[t] = cosf((float)t * (float)(M_PI / 64.0));
        float th = (float)t * (float)(M_PI / 128.0);
        s_cs[t] = cosf(th);
        s_sn[t] = sinf(th);
    }
    __syncthreads();

    // ---- phase 0b: ramp taps ----
    if (t < 128) {
        float sum = (t & 1) ? -64.f : 64.f;
        #pragma unroll
        for (int j = 1; j <= 63; ++j)
            sum = fmaf(2.f * (float)j, s_cos[(j * t) & 127], sum);
        s_h[t] = sum * (1.f / 16384.f);
    }
    __syncthreads();

    // ---- phase 0c: circular conv -> filtered slice rows s_g ----
    {
        const int s  = t >> 4;
        const int n0 = t & 15;
        float fa[8] = {0.f,0.f,0.f,0.f,0.f,0.f,0.f,0.f};
        const float* rawr = &s_raw[s * 129];
        for (int m = 0; m < WW; ++m) {
            float rm = rawr[m];
            int hb = (n0 - m) & 127;
            #pragma unroll
            for (int i = 0; i < 8; ++i)
                fa[i] = fmaf(rm, s_h[(hb + 16 * i) & 127], fa[i]);
        }
        #pragma unroll
        for (int i = 0; i < 8; ++i)
            s_g[s][n0 + 16 * i] = fa[i];
    }
    // chunk-0 top barrier covers s_g writes + death of s_raw/s_cos

    // ---- backprojection ----
    const int   Y  = t & 127;
    const int   xh = t >> 7;                 // X = q*64 + xh*32 + k, k=0..31
    const float yc = (float)Y - 63.5f;
    const float xc = (float)(q * 64 + xh * 32) - 63.5f;

    float acc[32];
    #pragma unroll
    for (int k = 0; k < 32; ++k) acc[k] = 0.f;

    #pragma unroll 1
    for (int ch = 0; ch < NANG / AB; ++ch) {
        __syncthreads();                     // rows free; s_g/s_cs visible
        // build AB rows: fp16 (p0,d) entries p=0..181, dup into 8B slots
        {
            const int aj   = t >> 4;
            const int lane = t & 15;
            const int a  = ch * AB + aj;
            const int i0 = a >> 3;
            const int i1 = (i0 + 1) & 15;
            const float w = (float)(a & 7) * 0.125f;
            const float* g0r = s_g[i0];
            const float* g1r = s_g[i1];
            unsigned* rr = &s_rows[aj * SLOTF];  // dword-indexed; slot s at dwords (s+1)*2
            #pragma unroll
            for (int pq = 0; pq < 12; ++pq) {
                int p = lane + 16 * pq;
                if (p < 182) {
                    int ix = p - PAD;
                    float v0 = 0.f, v1 = 0.f;
                    if ((unsigned)ix < 128u)
                        v0 = fmaf(w, g1r[ix] - g0r[ix], g0r[ix]);
                    int iy = ix + 1;
                    if ((unsigned)iy < 128u)
                        v1 = fmaf(w, g1r[iy] - g0r[iy], g0r[iy]);
                    unsigned eu = __builtin_bit_cast(unsigned,
                        __builtin_amdgcn_cvt_pkrtz(v0, v1 - v0));
                    rr[(p + 1) * 2]     = eu;   // slot p, lo dword
                    rr[p * 2 + 1]       = eu;   // slot p-1, hi dword
                }
            }
        }
        __syncthreads();

        #pragma unroll 1
        for (int j = 0; j < AB; ++j) {
            const int a = ch * AB + j;
            const float cs = s_cs[a];
            const float sn = s_sn[a];
            const bool  neg = (cs < 0.f);
            const float thr = neg ? 0.f : 1.f;
            // read slot = ii - (neg?1:0); slot s at byte (s+1)*8 within row
            const char* rowb = (const char*)&s_rows[j * SLOTF] + (neg ? 0 : 8);
            const float ub = fmaf(xc, cs, fmaf(yc, sn, 63.5f + (float)PAD));
            #pragma unroll
            for (int p = 0; p < 16; ++p) {
                float u0  = fmaf((float)(2 * p), cs, ub);
                int   ii  = (int)u0;                       // trunc==floor, u0>0
                float fr0 = __builtin_amdgcn_fractf(u0);
                uint2 wv  = *(const uint2*)(rowb + ii * 8); // ds_read_b64
                float tt  = fr0 + cs;
                float fr1 = __builtin_amdgcn_fractf(tt);
                unsigned s0 = neg ? wv.y : wv.x;
                unsigned s1 = (tt >= thr) ? wv.y : wv.x;
                // acc += p0 + fr*d   (p0 = f16 lo, d = f16 hi) via v_fma_mix
                asm("v_fma_mix_f32 %0, 1.0, %1, %0 op_sel:[0,0,0] op_sel_hi:[0,1,0]"
                    : "+v"(acc[2 * p]) : "v"(s0));
                asm("v_fma_mix_f32 %0, %1, %2, %0 op_sel:[0,1,0] op_sel_hi:[0,1,0]"
                    : "+v"(acc[2 * p]) : "v"(fr0), "v"(s0));
                asm("v_fma_mix_f32 %0, 1.0, %1, %0 op_sel:[0,0,0] op_sel_hi:[0,1,0]"
                    : "+v"(acc[2 * p + 1]) : "v"(s1));
                asm("v_fma_mix_f32 %0, %1, %2, %0 op_sel:[0,1,0] op_sel_hi:[0,1,0]"
                    : "+v"(acc[2 * p + 1]) : "v"(fr1), "v"(s1));
            }
        }
    }

    // ---- write out: vol[c,hh,X,Y] * (pi/128) ----
    float* ob = out + ((size_t)(c * 128 + hh) * 16384)
                    + (size_t)(q * 64 + xh * 32) * 128 + Y;
    const float scale = (float)(M_PI / 128.0);
    #pragma unroll
    for (int k = 0; k < 32; ++k)
        ob[(size_t)k * 128] = acc[k] * scale;
}

extern "C" void kernel_launch(void* const* d_in, const int* in_sizes, int n_in,
                              void* d_out, int out_size, void* d_ws, size_t ws_size,
                              hipStream_t stream) {
    const float* F = (const float*)d_in[0];
    float* out = (float*)d_out;
    fbp_fused<<<2048, 256, 0, stream>>>(F, out);
}

// Round 6
// 363.261 us; speedup vs baseline: 1.2167x; 1.2167x over previous
//
#include <hip/hip_runtime.h>
#include <math.h>

#ifndef M_PI
#define M_PI 3.14159265358979323846
#endif

// Geometry fixed by the reference
#define NSLICE 16
#define WW     128
#define GP     130      // s_g row pitch (floats)
#define PAD    27
#define KBIAS  90.5f    // 63.5 + PAD  (biased u = x*cs + y*sn + KBIAS > 0)
#define SMIR   181.0f   // 2*KBIAS: u(-p) = SMIR - u(p)
#define NSLOT  182      // slots 0..181; read ii in [0,180]
#define RSD    184      // row stride in dwords
#define PARTNER (16*RSD) // dword offset base row -> partner row (+64 angle)

// One block per (c,hh). 256 thr; thread owns 16 rot90-orbits (64 px).
// Quarter-rotation symmetry: u_{a+64}(r(p)) = u_a(p), r(X,Y)=(127-Y,X);
// one u/ii/fr/weight serves rows a and a+64 (same slot, +PARTNER offset).
// Rows = f16 (p_i, p_{i+1}) packed dwords; acc via v_dot2_f32_f16 (1/output).
__global__ __launch_bounds__(256, 4)
void fbp_fused(const float* __restrict__ F, float* __restrict__ out) {
    __shared__ __align__(16) unsigned s_rows[32 * RSD]; // 23552 B
    __shared__ float s_g[NSLICE][GP];                   // 8320 B
    __shared__ float s_h[WW];
    __shared__ float s_cs[64];
    __shared__ float s_sn[64];

    float* s_cos = (float*)s_rows;          // [128]    phase-0 overlay
    float* s_raw = (float*)s_rows + 128;    // [16*129] phase-0 overlay

    const int t   = threadIdx.x;
    const int blk = blockIdx.x;             // 0..1023
    const int hh  = blk & 127;
    const int c   = blk >> 7;

    // ---- phase 0a: stage 16 feature rows F[s,0,c,hh,:] + tables ----
    const float* Fb = F + (((size_t)c * 128 + hh) * 128);
    #pragma unroll
    for (int e = 0; e < 8; ++e) {
        int idx = t + 256 * e;
        int s = idx >> 7, m = idx & 127;
        s_raw[s * 129 + m] = Fb[(size_t)s * 131072 + m];
    }
    if (t < 128) {
        s_cos[t] = cosf((float)t * (float)(M_PI / 64.0));
        if (t < 64) {
            float th = (float)t * (float)(M_PI / 128.0);
            s_cs[t] = cosf(th);
            s_sn[t] = sinf(th);
        }
    }
    __syncthreads();

    // ---- phase 0b: ramp taps ----
    if (t < 128) {
        float sum = (t & 1) ? -64.f : 64.f;
        #pragma unroll
        for (int j = 1; j <= 63; ++j)
            sum = fmaf(2.f * (float)j, s_cos[(j * t) & 127], sum);
        s_h[t] = sum * (1.f / 16384.f);
    }
    __syncthreads();

    // ---- phase 0c: circular conv -> filtered slice rows s_g ----
    {
        const int s  = t >> 4;
        const int n0 = t & 15;
        float fa[8] = {0.f,0.f,0.f,0.f,0.f,0.f,0.f,0.f};
        const float* rawr = &s_raw[s * 129];
        for (int m = 0; m < WW; ++m) {
            float rm = rawr[m];
            int hb = (n0 - m) & 127;
            #pragma unroll
            for (int i = 0; i < 8; ++i)
                fa[i] = fmaf(rm, s_h[(hb + 16 * i) & 127], fa[i]);
        }
        #pragma unroll
        for (int i = 0; i < 8; ++i)
            s_g[s][n0 + 16 * i] = fa[i];
    }

    // ---- backprojection setup ----
    const int   l  = t & 63;                // lane: rep Y = l (0..63)
    const int   wv = t >> 6;                // wave: rep X = wv*16 + m
    const float yl = (float)l - 63.5f;      // in [-63.5,-0.5]

    float acc[64];
    #pragma unroll
    for (int k = 0; k < 64; ++k) acc[k] = 0.f;

    #pragma unroll 1
    for (int ch = 0; ch < 4; ++ch) {
        __syncthreads();   // covers filter->build (ch0) and gather->rebuild
        // build 32 rows: 16 base angles (ch*16+j) + 16 partners (+64)
        {
            const int r_id  = t >> 3;       // 0..31
            const int lane8 = t & 7;
            const int a  = ch * 16 + (r_id & 15) + ((r_id >> 4) ? 64 : 0);
            const int i0 = a >> 3;
            const int i1 = (i0 + 1) & 15;   // slice 16 wraps to 0
            const float w_ = (float)(a & 7) * 0.125f;
            const float* g0r = s_g[i0];
            const float* g1r = s_g[i1];
            unsigned* rr = &s_rows[r_id * RSD];
            #pragma unroll
            for (int qq = 0; qq < 23; ++qq) {
                int p = lane8 + 8 * qq;
                if (p < NSLOT) {
                    int ix = p - PAD;
                    float v0 = 0.f, v1 = 0.f;
                    if ((unsigned)ix < 128u)
                        v0 = fmaf(w_, g1r[ix] - g0r[ix], g0r[ix]);
                    int iy = ix + 1;
                    if ((unsigned)iy < 128u)
                        v1 = fmaf(w_, g1r[iy] - g0r[iy], g0r[iy]);
                    rr[p] = __builtin_bit_cast(unsigned,
                        __builtin_amdgcn_cvt_pkrtz(v0, v1));
                }
            }
        }
        __syncthreads();

        #pragma unroll 1
        for (int j = 0; j < 16; ++j) {
            const int a = ch * 16 + j;
            const float cs = s_cs[a];
            const float sn = s_sn[a];
            const float ay = fmaf(yl, sn, KBIAS);   // u(P0) partial
            const float by = fmaf(yl, -cs, KBIAS);  // u(P1) partial
            const unsigned* rowp = &s_rows[j * RSD];

            #pragma unroll
            for (int m = 0; m < 16; ++m) {
                const float xr = (float)(wv * 16 + m) - 63.5f;
                float u0 = fmaf(xr, cs, ay);  // u_a at P0=(X0,l)
                float u1 = fmaf(xr, sn, by);  // u_a at P1=r(P0)
                float u2 = SMIR - u0;         // u_a at P2=r2(P0)
                float u3 = SMIR - u1;         // u_a at P3=r3(P0)

                // sample u -> row_a feeds acc[ka], row_{a+64} feeds acc[kb]
                #define SAMPLE(U, KA, KB)                                     \
                do {                                                          \
                    int   ii = (int)(U);                                      \
                    float fr = __builtin_amdgcn_fractf(U);                    \
                    unsigned wa = rowp[ii];                                   \
                    unsigned wb = rowp[ii + PARTNER];                         \
                    unsigned wt = __builtin_bit_cast(unsigned,                \
                        __builtin_amdgcn_cvt_pkrtz(1.f - fr, fr));            \
                    asm("v_dot2_f32_f16 %0, %1, %2, %0"                       \
                        : "+v"(acc[KA]) : "v"(wt), "v"(wa));                  \
                    asm("v_dot2_f32_f16 %0, %1, %2, %0"                       \
                        : "+v"(acc[KB]) : "v"(wt), "v"(wb));                  \
                } while (0)

                SAMPLE(u0, 4*m + 0, 4*m + 1);
                SAMPLE(u1, 4*m + 1, 4*m + 2);
                SAMPLE(u2, 4*m + 2, 4*m + 3);
                SAMPLE(u3, 4*m + 3, 4*m + 0);
                #undef SAMPLE
            }
        }
    }

    // ---- write out: vol[c,hh,X,Y] * (pi/128) ----
    float* ob = out + (size_t)blk * 16384;
    const float sc = (float)(M_PI / 128.0);
    #pragma unroll
    for (int m = 0; m < 16; ++m) {
        const int X0 = wv * 16 + m;
        ob[X0 * 128 + l]                 = acc[4*m + 0] * sc; // P0 (coalesced)
        ob[(127 - l) * 128 + X0]         = acc[4*m + 1] * sc; // P1
        ob[(127 - X0) * 128 + (127 - l)] = acc[4*m + 2] * sc; // P2 (coalesced)
        ob[l * 128 + (127 - X0)]         = acc[4*m + 3] * sc; // P3
    }
}

extern "C" void kernel_launch(void* const* d_in, const int* in_sizes, int n_in,
                              void* d_out, int out_size, void* d_ws, size_t ws_size,
                              hipStream_t stream) {
    const float* F = (const float*)d_in[0];
    float* out = (float*)d_out;
    fbp_fused<<<1024, 256, 0, stream>>>(F, out);
}

// Round 8
// 309.226 us; speedup vs baseline: 1.4293x; 1.1747x over previous
//
#include <hip/hip_runtime.h>
#include <math.h>

#ifndef M_PI
#define M_PI 3.14159265358979323846
#endif

#define GP     130
#define PAD    27
#define KBIAS  90.5f     // 63.5 + PAD
#define SMIR   181.0f    // 2*KBIAS
#define NSLOT  182
#define RSD    184       // dwords per row
#define NROWS  34        // 8 groups x 4 rows + special rows 0,64

// One block per (c,hh), 512 threads, 8 reps/thread (rep quarter [0,64)^2).
// D4 symmetry: u_a(Q) feeds rows {a,64-a,a+64,128-a} at pixels
// {Q, swapQ, rQ, MQ}; rot-accs R[8][4] + mirror-accs S[8][4]; S folded into
// owners' R via LDS inbox exchange. Rows = f16 (p_i,p_{i+1}); v_dot2_f32_f16.
// a=32 group degenerates to {32,32,96,96}: its rows stored HALVED so the
// double accumulation sums to the exact single contribution.
__global__ __launch_bounds__(512, 4)
void fbp_fused(const float* __restrict__ F, float* __restrict__ out) {
    __shared__ __align__(16) unsigned s_rows[NROWS * RSD]; // 25024 B (+inbox overlay)
    __shared__ float s_g[16][GP];
    __shared__ float s_h[128];
    __shared__ float s_cs[34];
    __shared__ float s_sn[34];

    float* s_cos = (float*)s_rows;          // [128]    phase-0 overlay
    float* s_raw = (float*)s_rows + 128;    // [16*129] phase-0 overlay
    float* inbox = (float*)s_rows;          // exchange overlay (s_rows dead)

    const int t   = threadIdx.x;
    const int blk = blockIdx.x;             // 0..1023
    const int hh  = blk & 127;
    const int c   = blk >> 7;

    // ---- stage 16 feature rows + tables ----
    const float* Fb = F + (((size_t)c * 128 + hh) * 128);
    #pragma unroll
    for (int e = 0; e < 4; ++e) {
        int idx = t + 512 * e;
        int s = idx >> 7, m = idx & 127;
        s_raw[s * 129 + m] = Fb[(size_t)s * 131072 + m];
    }
    if (t < 128) s_cos[t] = cosf((float)t * (float)(M_PI / 64.0));
    if (t < 34) {
        float th = (float)t * (float)(M_PI / 128.0);
        s_cs[t] = cosf(th);
        s_sn[t] = sinf(th);
    }
    __syncthreads();

    // ---- ramp taps ----
    if (t < 128) {
        float sum = (t & 1) ? -64.f : 64.f;
        #pragma unroll
        for (int j = 1; j <= 63; ++j)
            sum = fmaf(2.f * (float)j, s_cos[(j * t) & 127], sum);
        s_h[t] = sum * (1.f / 16384.f);
    }
    __syncthreads();

    // ---- circular conv -> filtered slice rows s_g ----
    {
        const int s  = t >> 5;
        const int n0 = t & 31;
        float fa[4] = {0.f, 0.f, 0.f, 0.f};
        const float* rawr = &s_raw[s * 129];
        for (int m = 0; m < 128; ++m) {
            float rm = rawr[m];
            int hb = (n0 - m) & 127;
            #pragma unroll
            for (int i = 0; i < 4; ++i)
                fa[i] = fmaf(rm, s_h[(hb + 32 * i) & 127], fa[i]);
        }
        #pragma unroll
        for (int i = 0; i < 4; ++i)
            s_g[s][n0 + 32 * i] = fa[i];
    }

    // ---- backprojection ----
    const int   l  = t & 63;
    const int   w8 = t >> 6;                // rep X0 = w8*8 + m
    const float yl = (float)l - 63.5f;

    float R[8][4], S[8][4];
    #pragma unroll
    for (int m = 0; m < 8; ++m)
        #pragma unroll
        for (int k = 0; k < 4; ++k) { R[m][k] = 0.f; S[m][k] = 0.f; }

    #pragma unroll 1
    for (int ch = 0; ch < 4; ++ch) {
        __syncthreads();   // prev gather done / conv done; s_rows writable
        // build 32 rows: group g rows {a,64-a,a+64,128-a} at slots 4g+j
        {
            const int r_id   = t >> 4;      // 0..31
            const int lane16 = t & 15;
            const int g = r_id >> 2, j = r_id & 3;
            const int a = ch * 8 + g + 1;
            const int row = (j == 0) ? a : (j == 1) ? 64 - a
                          : (j == 2) ? a + 64 : 128 - a;
            const int i0 = row >> 3;
            const int i1 = (i0 + 1) & 15;
            const float w_ = (float)(row & 7) * 0.125f;
            const float hs = (a == 32) ? 0.5f : 1.0f;  // degenerate-orbit fix
            const float* g0r = s_g[i0];
            const float* g1r = s_g[i1];
            unsigned* rr = &s_rows[r_id * RSD];
            #pragma unroll
            for (int qq = 0; qq < 12; ++qq) {
                int p = lane16 + 16 * qq;
                if (p < NSLOT) {
                    int ix = p - PAD;
                    float v0 = 0.f, v1 = 0.f;
                    if ((unsigned)ix < 128u)
                        v0 = fmaf(w_, g1r[ix] - g0r[ix], g0r[ix]);
                    int iy = ix + 1;
                    if ((unsigned)iy < 128u)
                        v1 = fmaf(w_, g1r[iy] - g0r[iy], g0r[iy]);
                    rr[p] = __builtin_bit_cast(unsigned,
                        __builtin_amdgcn_cvt_pkrtz(v0 * hs, v1 * hs));
                }
            }
        }
        if (ch == 0 && t < 32) {            // special rows 0, 64 at slots 32,33
            const int r2 = t >> 4;          // 0 or 1
            const int lane16 = t & 15;
            const int row = r2 * 64;
            const int i0 = row >> 3;
            const float* g0r = s_g[i0];
            unsigned* rr = &s_rows[(32 + r2) * RSD];
            #pragma unroll
            for (int qq = 0; qq < 12; ++qq) {
                int p = lane16 + 16 * qq;
                if (p < NSLOT) {
                    int ix = p - PAD;
                    float v0 = ((unsigned)ix < 128u) ? g0r[ix] : 0.f;
                    int iy = ix + 1;
                    float v1 = ((unsigned)iy < 128u) ? g0r[iy] : 0.f;
                    rr[p] = __builtin_bit_cast(unsigned,
                        __builtin_amdgcn_cvt_pkrtz(v0, v1));
                }
            }
        }
        __syncthreads();

        #define SAMPLE4(U, RA, RB, SA, SB) do {                               \
            int   ii = (int)(U);                                              \
            float fr = __builtin_amdgcn_fractf(U);                            \
            unsigned wt = __builtin_bit_cast(unsigned,                        \
                __builtin_amdgcn_cvt_pkrtz(1.f - fr, fr));                    \
            const unsigned* pp = rowp + ii;                                   \
            unsigned w0 = pp[0];                                              \
            unsigned w1 = pp[RSD];                                            \
            unsigned w2 = pp[2 * RSD];                                        \
            unsigned w3 = pp[3 * RSD];                                        \
            asm("v_dot2_f32_f16 %0, %1, %2, %0" : "+v"(RA) : "v"(wt), "v"(w0));\
            asm("v_dot2_f32_f16 %0, %1, %2, %0" : "+v"(RB) : "v"(wt), "v"(w2));\
            asm("v_dot2_f32_f16 %0, %1, %2, %0" : "+v"(SA) : "v"(wt), "v"(w3));\
            asm("v_dot2_f32_f16 %0, %1, %2, %0" : "+v"(SB) : "v"(wt), "v"(w1));\
        } while (0)

        #pragma unroll 1
        for (int g = 0; g < 8; ++g) {
            const int a = ch * 8 + g + 1;
            const float cs = s_cs[a];
            const float sn = s_sn[a];
            const float ay = fmaf(yl, sn, KBIAS);
            const float by = fmaf(yl, -cs, KBIAS);
            const unsigned* rowp = &s_rows[(4 * g) * RSD];
            #pragma unroll
            for (int m = 0; m < 8; ++m) {
                const float xr = (float)(w8 * 8 + m) - 63.5f;
                float uA = fmaf(xr, cs, ay);
                float uB = fmaf(xr, sn, by);
                float uC = SMIR - uA;
                float uD = SMIR - uB;
                SAMPLE4(uA, R[m][0], R[m][1], S[m][0], S[m][3]);
                SAMPLE4(uB, R[m][1], R[m][2], S[m][3], S[m][2]);
                SAMPLE4(uC, R[m][2], R[m][3], S[m][2], S[m][1]);
                SAMPLE4(uD, R[m][3], R[m][0], S[m][1], S[m][0]);
            }
        }

        if (ch == 0) {                      // special group: rows 0 (slot32), 64 (slot33)
            const float by = fmaf(yl, -1.f, KBIAS);
            const unsigned* rowp = &s_rows[32 * RSD];
            #define SAMPLE2(U, RA, RB) do {                                   \
                int   ii = (int)(U);                                          \
                float fr = __builtin_amdgcn_fractf(U);                        \
                unsigned wt = __builtin_bit_cast(unsigned,                    \
                    __builtin_amdgcn_cvt_pkrtz(1.f - fr, fr));                \
                const unsigned* pp = rowp + ii;                               \
                unsigned w0 = pp[0];                                          \
                unsigned w1 = pp[RSD];                                        \
                asm("v_dot2_f32_f16 %0, %1, %2, %0" : "+v"(RA) : "v"(wt), "v"(w0));\
                asm("v_dot2_f32_f16 %0, %1, %2, %0" : "+v"(RB) : "v"(wt), "v"(w1));\
            } while (0)
            #pragma unroll
            for (int m = 0; m < 8; ++m) {
                const float xr = (float)(w8 * 8 + m) - 63.5f;
                float uA = xr + KBIAS;
                float uB = by;
                float uC = SMIR - uA;
                float uD = SMIR - uB;
                SAMPLE2(uA, R[m][0], R[m][1]);
                SAMPLE2(uB, R[m][1], R[m][2]);
                SAMPLE2(uC, R[m][2], R[m][3]);
                SAMPLE2(uD, R[m][3], R[m][0]);
            }
            #undef SAMPLE2
        }
        #undef SAMPLE4
    }

    // ---- fold mirror accs into owners: 4 LDS exchange rounds ----
    // S[m][k] = partial for pixel r^k(M Q_m) = r^(k+1) of rep' (l, X0_m),
    // owned by thread (w8'=l>>3, l'=X0_m), its rep index m'=l&7.
    #pragma unroll
    for (int k = 0; k < 4; ++k) {
        __syncthreads();                    // prior reads (or gather) done
        #pragma unroll
        for (int m = 0; m < 8; ++m)
            inbox[(l >> 3) * 577 + (w8 * 8 + m) * 9 + (l & 7)] = S[m][k];
        __syncthreads();
        #pragma unroll
        for (int m = 0; m < 8; ++m)
            R[m][(k + 1) & 3] += inbox[w8 * 577 + l * 9 + m];
    }

    // ---- write out: pixels r^k(Q_m), Q_m = (X0, l) ----
    float* ob = out + (size_t)blk * 16384;
    const float sc = (float)(M_PI / 128.0);
    #pragma unroll
    for (int m = 0; m < 8; ++m) {
        const int X0 = w8 * 8 + m;
        ob[X0 * 128 + l]                 = R[m][0] * sc;
        ob[(127 - l) * 128 + X0]         = R[m][1] * sc;
        ob[(127 - X0) * 128 + (127 - l)] = R[m][2] * sc;
        ob[l * 128 + (127 - X0)]         = R[m][3] * sc;
    }
}

extern "C" void kernel_launch(void* const* d_in, const int* in_sizes, int n_in,
                              void* d_out, int out_size, void* d_ws, size_t ws_size,
                              hipStream_t stream) {
    const float* F = (const float*)d_in[0];
    float* out = (float*)d_out;
    fbp_fused<<<1024, 512, 0, stream>>>(F, out);
}